// Round 1
// baseline (458.174 us; speedup 1.0000x reference)
//
#include <hip/hip_runtime.h>
#include <hip/hip_bf16.h>

#define BB 16
#define TT 2048
#define VV 512

typedef __attribute__((ext_vector_type(8))) short short8;
typedef __attribute__((ext_vector_type(4))) float floatx4;

#define LDT 40  // padded LDS row pitch in shorts (80B: breaks pow2 bank strides)

static __device__ inline ushort f2bf(float f) {
  __hip_bfloat16 h = __float2bfloat16(f);
  return *(ushort*)&h;
}

// WqT[u][v] = Wq[v][u], bf16
__global__ __launch_bounds__(256) void k_transpose_wq(const float* __restrict__ Wq,
                                                      ushort* __restrict__ WqT) {
  int u = blockIdx.x;
  for (int v = threadIdx.x; v < VV; v += blockDim.x)
    WqT[u * VV + v] = f2bf(Wq[(size_t)v * VV + u]);
}

// l1[b,t,v] = sum_{p<=t, idx[b,p]==v} h[t-p]   (bf16 out)
__global__ __launch_bounds__(64) void k_build_l1(const int* __restrict__ idx,
                                                 const float* __restrict__ h,
                                                 ushort* __restrict__ l1) {
  int bt = blockIdx.x;
  int b = bt >> 11, t = bt & (TT - 1);
  __shared__ float acc[VV];
  for (int v = threadIdx.x; v < VV; v += 64) acc[v] = 0.f;
  __syncthreads();
  const int* row = idx + b * TT;
  for (int p = threadIdx.x; p <= t; p += 64)
    atomicAdd(&acc[row[p]], h[t - p]);
  __syncthreads();
  ushort* out = l1 + (size_t)bt * VV;
  for (int v = threadIdx.x; v < VV; v += 64) out[v] = f2bf(acc[v]);
}

// VvT[b][j][s] = Wv[j][idx[b,s]]   (bf16, (B,V,T) layout => k-contiguous B operand)
__global__ __launch_bounds__(256) void k_build_vvt(const int* __restrict__ idx,
                                                   const float* __restrict__ Wv,
                                                   ushort* __restrict__ VvT) {
  int bj = blockIdx.x;
  int b = bj >> 9, j = bj & (VV - 1);
  __shared__ float wrow[VV];
  for (int v = threadIdx.x; v < VV; v += blockDim.x) wrow[v] = Wv[(size_t)j * VV + v];
  __syncthreads();
  const int* row = idx + b * TT;
  ushort* out = VvT + (size_t)bj * TT;
  for (int s = threadIdx.x; s < TT; s += blockDim.x)
    out[s] = f2bf(wrow[row[s]]);
}

// a2[b,t,s] = tril( Q[b,t,:] . l1[b,s,:] )   Q row = WqT[idx[b,t]]
// 128x128 C-tile, K=512, 4 waves each 64x64 (4x4 of 16x16x32 mfma)
__global__ __launch_bounds__(256) void k_gemm1(const int* __restrict__ idx,
                                               const ushort* __restrict__ WqT,
                                               const ushort* __restrict__ l1,
                                               ushort* __restrict__ a2) {
  const int s_t = blockIdx.x, t_t = blockIdx.y, b = blockIdx.z;
  if (s_t > t_t) return;  // strictly-upper tiles never read downstream
  const int t0 = t_t << 7, s0 = s_t << 7;

  __shared__ __attribute__((aligned(16))) short As[128 * LDT];
  __shared__ __attribute__((aligned(16))) short Bs[128 * LDT];

  const int tid = threadIdx.x;
  const int lane = tid & 63, wid = tid >> 6;
  const int wm = wid & 1, wn = wid >> 1;
  const int quad = lane >> 4, ln = lane & 15;

  floatx4 acc[4][4];
#pragma unroll
  for (int i = 0; i < 4; i++)
#pragma unroll
    for (int j = 0; j < 4; j++) acc[i][j] = (floatx4){0.f, 0.f, 0.f, 0.f};

  const int rr = tid >> 2;          // staging row 0..63 (and +64)
  const int cc = (tid & 3) << 3;    // staging col chunk (8 shorts)

  const int u0 = idx[b * TT + t0 + rr];
  const int u1 = idx[b * TT + t0 + rr + 64];
  const ushort* a_src0 = WqT + (size_t)u0 * VV + cc;
  const ushort* a_src1 = WqT + (size_t)u1 * VV + cc;
  const ushort* b_src0 = l1 + ((size_t)(b * TT + s0 + rr)) * VV + cc;
  const ushort* b_src1 = l1 + ((size_t)(b * TT + s0 + rr + 64)) * VV + cc;
  short* a_dst0 = &As[rr * LDT + cc];
  short* a_dst1 = &As[(rr + 64) * LDT + cc];
  short* b_dst0 = &Bs[rr * LDT + cc];
  short* b_dst1 = &Bs[(rr + 64) * LDT + cc];

#pragma unroll 1
  for (int kt = 0; kt < 16; ++kt) {
    const int v0 = kt << 5;
    *(short8*)a_dst0 = *(const short8*)(a_src0 + v0);
    *(short8*)a_dst1 = *(const short8*)(a_src1 + v0);
    *(short8*)b_dst0 = *(const short8*)(b_src0 + v0);
    *(short8*)b_dst1 = *(const short8*)(b_src1 + v0);
    __syncthreads();
    short8 af[4], bf[4];
#pragma unroll
    for (int i = 0; i < 4; i++)
      af[i] = *(const short8*)&As[(wm * 64 + i * 16 + ln) * LDT + quad * 8];
#pragma unroll
    for (int j = 0; j < 4; j++)
      bf[j] = *(const short8*)&Bs[(wn * 64 + j * 16 + ln) * LDT + quad * 8];
#pragma unroll
    for (int i = 0; i < 4; i++)
#pragma unroll
      for (int j = 0; j < 4; j++)
        acc[i][j] = __builtin_amdgcn_mfma_f32_16x16x32_bf16(af[i], bf[j], acc[i][j], 0, 0, 0);
    __syncthreads();
  }

#pragma unroll
  for (int i = 0; i < 4; i++)
#pragma unroll
    for (int j = 0; j < 4; j++) {
      const int rowb = t0 + wm * 64 + i * 16 + quad * 4;
      const int col = s0 + wn * 64 + j * 16 + ln;
#pragma unroll
      for (int r = 0; r < 4; r++) {
        const int row = rowb + r;
        float v = acc[i][j][r];
        if (col > row) v = 0.f;  // causal mask on diagonal tiles
        a2[((size_t)(b * TT + row)) * TT + col] = f2bf(v);
      }
    }
}

// logits[b,t,j] = sum_{s<t0+128} a2[b,t,s] * VvT[b,j,s]   (fp32 out)
__global__ __launch_bounds__(256) void k_gemm2(const ushort* __restrict__ a2,
                                               const ushort* __restrict__ VvT,
                                               float* __restrict__ out) {
  const int j_t = blockIdx.x, t_t = blockIdx.y, b = blockIdx.z;
  const int t0 = t_t << 7, j0 = j_t << 7;
  const int nk = (t_t << 2) + 4;  // K-loop only to the diagonal block

  __shared__ __attribute__((aligned(16))) short As[128 * LDT];
  __shared__ __attribute__((aligned(16))) short Bs[128 * LDT];

  const int tid = threadIdx.x;
  const int lane = tid & 63, wid = tid >> 6;
  const int wm = wid & 1, wn = wid >> 1;
  const int quad = lane >> 4, ln = lane & 15;

  floatx4 acc[4][4];
#pragma unroll
  for (int i = 0; i < 4; i++)
#pragma unroll
    for (int j = 0; j < 4; j++) acc[i][j] = (floatx4){0.f, 0.f, 0.f, 0.f};

  const int rr = tid >> 2;
  const int cc = (tid & 3) << 3;

  const ushort* a_src0 = a2 + ((size_t)(b * TT + t0 + rr)) * TT + cc;
  const ushort* a_src1 = a2 + ((size_t)(b * TT + t0 + rr + 64)) * TT + cc;
  const ushort* b_src0 = VvT + ((size_t)(b * VV + j0 + rr)) * TT + cc;
  const ushort* b_src1 = VvT + ((size_t)(b * VV + j0 + rr + 64)) * TT + cc;
  short* a_dst0 = &As[rr * LDT + cc];
  short* a_dst1 = &As[(rr + 64) * LDT + cc];
  short* b_dst0 = &Bs[rr * LDT + cc];
  short* b_dst1 = &Bs[(rr + 64) * LDT + cc];

#pragma unroll 1
  for (int kt = 0; kt < nk; ++kt) {
    const int soff = kt << 5;
    *(short8*)a_dst0 = *(const short8*)(a_src0 + soff);
    *(short8*)a_dst1 = *(const short8*)(a_src1 + soff);
    *(short8*)b_dst0 = *(const short8*)(b_src0 + soff);
    *(short8*)b_dst1 = *(const short8*)(b_src1 + soff);
    __syncthreads();
    short8 af[4], bf[4];
#pragma unroll
    for (int i = 0; i < 4; i++)
      af[i] = *(const short8*)&As[(wm * 64 + i * 16 + ln) * LDT + quad * 8];
#pragma unroll
    for (int j = 0; j < 4; j++)
      bf[j] = *(const short8*)&Bs[(wn * 64 + j * 16 + ln) * LDT + quad * 8];
#pragma unroll
    for (int i = 0; i < 4; i++)
#pragma unroll
      for (int j = 0; j < 4; j++)
        acc[i][j] = __builtin_amdgcn_mfma_f32_16x16x32_bf16(af[i], bf[j], acc[i][j], 0, 0, 0);
    __syncthreads();
  }

#pragma unroll
  for (int i = 0; i < 4; i++)
#pragma unroll
    for (int j = 0; j < 4; j++) {
      const int rowb = t0 + wm * 64 + i * 16 + quad * 4;
      const int col = j0 + wn * 64 + j * 16 + ln;
#pragma unroll
      for (int r = 0; r < 4; r++)
        out[((size_t)(b * TT + rowb + r)) * VV + col] = acc[i][j][r];
    }
}

extern "C" void kernel_launch(void* const* d_in, const int* in_sizes, int n_in,
                              void* d_out, int out_size, void* d_ws, size_t ws_size,
                              hipStream_t stream) {
  const int* idx = (const int*)d_in[0];
  const float* pos_table = (const float*)d_in[1];  // h[0..T-1]
  const float* Wq = (const float*)d_in[2];
  const float* Wv = (const float*)d_in[3];
  float* out = (float*)d_out;

  char* ws = (char*)d_ws;
  // ws layout (bytes):
  //   WqT  bf16 (V,V)      :       0 ..   524288
  //   l1   bf16 (B,T,V)    :  524288 .. 34078720
  //   VvT  bf16 (B,V,T)    : 34078720 .. 67633152
  //   a2   bf16 (B,T,T)    : 67633152 .. 201850880   (~193 MB total)
  ushort* WqT = (ushort*)(ws);
  ushort* l1 = (ushort*)(ws + 524288);
  ushort* VvT = (ushort*)(ws + 34078720UL);
  ushort* a2 = (ushort*)(ws + 67633152UL);

  k_transpose_wq<<<dim3(VV), 256, 0, stream>>>(Wq, WqT);
  k_build_l1<<<dim3(BB * TT), 64, 0, stream>>>(idx, pos_table, l1);
  k_build_vvt<<<dim3(BB * VV), 256, 0, stream>>>(idx, Wv, VvT);
  k_gemm1<<<dim3(16, 16, BB), 256, 0, stream>>>(idx, WqT, l1, a2);
  k_gemm2<<<dim3(4, 16, BB), 256, 0, stream>>>(a2, VvT, out);
}

// Round 2
// 373.024 us; speedup vs baseline: 1.2283x; 1.2283x over previous
//
#include <hip/hip_runtime.h>
#include <hip/hip_bf16.h>

#define BB 16
#define TT 2048
#define VV 512

typedef __attribute__((ext_vector_type(8))) short short8;
typedef __attribute__((ext_vector_type(4))) float floatx4;

#define LDT 40  // padded LDS row pitch in shorts (80B: breaks pow2 bank strides)

static __device__ inline ushort f2bf(float f) {
  __hip_bfloat16 h = __float2bfloat16(f);
  return *(ushort*)&h;
}

// WqT[u][v] = Wq[v][u], bf16
__global__ __launch_bounds__(256) void k_transpose_wq(const float* __restrict__ Wq,
                                                      ushort* __restrict__ WqT) {
  int u = blockIdx.x;
  for (int v = threadIdx.x; v < VV; v += blockDim.x)
    WqT[u * VV + v] = f2bf(Wq[(size_t)v * VV + u]);
}

// PE[t][p] = (p <= t) ? bf16(h[t-p]) : 0   -- (T,T) bf16, shared across batch
__global__ __launch_bounds__(256) void k_build_pe(const float* __restrict__ h,
                                                  ushort* __restrict__ PE) {
  int t = blockIdx.x;
  ushort* out = PE + (size_t)t * TT;
  for (int p = threadIdx.x; p < TT; p += blockDim.x)
    out[p] = (p <= t) ? f2bf(h[t - p]) : (ushort)0;
}

// ET[b][v][p] = (idx[b,p] == v) ? 1.0bf16 : 0   -- (B,V,T) bf16, k-contiguous
__global__ __launch_bounds__(256) void k_build_et(const int* __restrict__ idx,
                                                  ushort* __restrict__ ET) {
  int bv = blockIdx.x;
  int b = bv >> 9, v = bv & (VV - 1);
  const int* row = idx + b * TT;
  ushort* out = ET + (size_t)bv * TT;
  for (int s4 = threadIdx.x * 4; s4 < TT; s4 += blockDim.x * 4) {
    int4 iv = *(const int4*)(row + s4);
    ushort4 o;
    o.x = (iv.x == v) ? (ushort)0x3F80 : (ushort)0;
    o.y = (iv.y == v) ? (ushort)0x3F80 : (ushort)0;
    o.z = (iv.z == v) ? (ushort)0x3F80 : (ushort)0;
    o.w = (iv.w == v) ? (ushort)0x3F80 : (ushort)0;
    *(ushort4*)(out + s4) = o;
  }
}

// VvT[b][j][s] = Wv[j][idx[b,s]]   (bf16, (B,V,T) layout => k-contiguous B operand)
__global__ __launch_bounds__(256) void k_build_vvt(const int* __restrict__ idx,
                                                   const float* __restrict__ Wv,
                                                   ushort* __restrict__ VvT) {
  int bj = blockIdx.x;
  int b = bj >> 9, j = bj & (VV - 1);
  __shared__ float wrow[VV];
  for (int v = threadIdx.x; v < VV; v += blockDim.x) wrow[v] = Wv[(size_t)j * VV + v];
  __syncthreads();
  const int* row = idx + b * TT;
  ushort* out = VvT + (size_t)bj * TT;
  for (int s = threadIdx.x; s < TT; s += blockDim.x)
    out[s] = f2bf(wrow[row[s]]);
}

// l1[b,t,v] = sum_p PE[t,p] * ET[b,v,p]   (bf16 out), K only to diagonal block
__global__ __launch_bounds__(256) void k_gemm_l1(const ushort* __restrict__ PE,
                                                 const ushort* __restrict__ ET,
                                                 ushort* __restrict__ l1) {
  const int v_t = blockIdx.x, t_t = blockIdx.y, b = blockIdx.z;
  const int t0 = t_t << 7, v0 = v_t << 7;
  const int nk = (t_t << 2) + 4;  // p runs to t0+127

  __shared__ __attribute__((aligned(16))) short As[128 * LDT];
  __shared__ __attribute__((aligned(16))) short Bs[128 * LDT];

  const int tid = threadIdx.x;
  const int lane = tid & 63, wid = tid >> 6;
  const int wm = wid & 1, wn = wid >> 1;
  const int quad = lane >> 4, ln = lane & 15;

  floatx4 acc[4][4];
#pragma unroll
  for (int i = 0; i < 4; i++)
#pragma unroll
    for (int j = 0; j < 4; j++) acc[i][j] = (floatx4){0.f, 0.f, 0.f, 0.f};

  const int rr = tid >> 2;
  const int cc = (tid & 3) << 3;

  const ushort* a_src0 = PE + (size_t)(t0 + rr) * TT + cc;
  const ushort* a_src1 = PE + (size_t)(t0 + rr + 64) * TT + cc;
  const ushort* b_src0 = ET + ((size_t)(b * VV + v0 + rr)) * TT + cc;
  const ushort* b_src1 = ET + ((size_t)(b * VV + v0 + rr + 64)) * TT + cc;
  short* a_dst0 = &As[rr * LDT + cc];
  short* a_dst1 = &As[(rr + 64) * LDT + cc];
  short* b_dst0 = &Bs[rr * LDT + cc];
  short* b_dst1 = &Bs[(rr + 64) * LDT + cc];

#pragma unroll 1
  for (int kt = 0; kt < nk; ++kt) {
    const int poff = kt << 5;
    *(short8*)a_dst0 = *(const short8*)(a_src0 + poff);
    *(short8*)a_dst1 = *(const short8*)(a_src1 + poff);
    *(short8*)b_dst0 = *(const short8*)(b_src0 + poff);
    *(short8*)b_dst1 = *(const short8*)(b_src1 + poff);
    __syncthreads();
    short8 af[4], bf[4];
#pragma unroll
    for (int i = 0; i < 4; i++)
      af[i] = *(const short8*)&As[(wm * 64 + i * 16 + ln) * LDT + quad * 8];
#pragma unroll
    for (int j = 0; j < 4; j++)
      bf[j] = *(const short8*)&Bs[(wn * 64 + j * 16 + ln) * LDT + quad * 8];
#pragma unroll
    for (int i = 0; i < 4; i++)
#pragma unroll
      for (int j = 0; j < 4; j++)
        acc[i][j] = __builtin_amdgcn_mfma_f32_16x16x32_bf16(af[i], bf[j], acc[i][j], 0, 0, 0);
    __syncthreads();
  }

#pragma unroll
  for (int i = 0; i < 4; i++)
#pragma unroll
    for (int j = 0; j < 4; j++) {
      const int rowb = t0 + wm * 64 + i * 16 + quad * 4;
      const int col = v0 + wn * 64 + j * 16 + ln;
#pragma unroll
      for (int r = 0; r < 4; r++)
        l1[((size_t)(b * TT + rowb + r)) * VV + col] = f2bf(acc[i][j][r]);
    }
}

// a2[b,t,s] = tril( Q[b,t,:] . l1[b,s,:] )   Q row = WqT[idx[b,t]]
__global__ __launch_bounds__(256) void k_gemm1(const int* __restrict__ idx,
                                               const ushort* __restrict__ WqT,
                                               const ushort* __restrict__ l1,
                                               ushort* __restrict__ a2) {
  const int s_t = blockIdx.x, t_t = blockIdx.y, b = blockIdx.z;
  if (s_t > t_t) return;  // strictly-upper tiles never read downstream
  const int t0 = t_t << 7, s0 = s_t << 7;

  __shared__ __attribute__((aligned(16))) short As[128 * LDT];
  __shared__ __attribute__((aligned(16))) short Bs[128 * LDT];

  const int tid = threadIdx.x;
  const int lane = tid & 63, wid = tid >> 6;
  const int wm = wid & 1, wn = wid >> 1;
  const int quad = lane >> 4, ln = lane & 15;

  floatx4 acc[4][4];
#pragma unroll
  for (int i = 0; i < 4; i++)
#pragma unroll
    for (int j = 0; j < 4; j++) acc[i][j] = (floatx4){0.f, 0.f, 0.f, 0.f};

  const int rr = tid >> 2;
  const int cc = (tid & 3) << 3;

  const int u0 = idx[b * TT + t0 + rr];
  const int u1 = idx[b * TT + t0 + rr + 64];
  const ushort* a_src0 = WqT + (size_t)u0 * VV + cc;
  const ushort* a_src1 = WqT + (size_t)u1 * VV + cc;
  const ushort* b_src0 = l1 + ((size_t)(b * TT + s0 + rr)) * VV + cc;
  const ushort* b_src1 = l1 + ((size_t)(b * TT + s0 + rr + 64)) * VV + cc;
  short* a_dst0 = &As[rr * LDT + cc];
  short* a_dst1 = &As[(rr + 64) * LDT + cc];
  short* b_dst0 = &Bs[rr * LDT + cc];
  short* b_dst1 = &Bs[(rr + 64) * LDT + cc];

#pragma unroll 1
  for (int kt = 0; kt < 16; ++kt) {
    const int v0 = kt << 5;
    *(short8*)a_dst0 = *(const short8*)(a_src0 + v0);
    *(short8*)a_dst1 = *(const short8*)(a_src1 + v0);
    *(short8*)b_dst0 = *(const short8*)(b_src0 + v0);
    *(short8*)b_dst1 = *(const short8*)(b_src1 + v0);
    __syncthreads();
    short8 af[4], bf[4];
#pragma unroll
    for (int i = 0; i < 4; i++)
      af[i] = *(const short8*)&As[(wm * 64 + i * 16 + ln) * LDT + quad * 8];
#pragma unroll
    for (int j = 0; j < 4; j++)
      bf[j] = *(const short8*)&Bs[(wn * 64 + j * 16 + ln) * LDT + quad * 8];
#pragma unroll
    for (int i = 0; i < 4; i++)
#pragma unroll
      for (int j = 0; j < 4; j++)
        acc[i][j] = __builtin_amdgcn_mfma_f32_16x16x32_bf16(af[i], bf[j], acc[i][j], 0, 0, 0);
    __syncthreads();
  }

#pragma unroll
  for (int i = 0; i < 4; i++)
#pragma unroll
    for (int j = 0; j < 4; j++) {
      const int rowb = t0 + wm * 64 + i * 16 + quad * 4;
      const int col = s0 + wn * 64 + j * 16 + ln;
#pragma unroll
      for (int r = 0; r < 4; r++) {
        const int row = rowb + r;
        float v = acc[i][j][r];
        if (col > row) v = 0.f;  // causal mask on diagonal tiles
        a2[((size_t)(b * TT + row)) * TT + col] = f2bf(v);
      }
    }
}

// logits[b,t,j] = sum_{s<t0+128} a2[b,t,s] * VvT[b,j,s]   (fp32 out)
__global__ __launch_bounds__(256) void k_gemm2(const ushort* __restrict__ a2,
                                               const ushort* __restrict__ VvT,
                                               float* __restrict__ out) {
  const int j_t = blockIdx.x, t_t = blockIdx.y, b = blockIdx.z;
  const int t0 = t_t << 7, j0 = j_t << 7;
  const int nk = (t_t << 2) + 4;  // K-loop only to the diagonal block

  __shared__ __attribute__((aligned(16))) short As[128 * LDT];
  __shared__ __attribute__((aligned(16))) short Bs[128 * LDT];

  const int tid = threadIdx.x;
  const int lane = tid & 63, wid = tid >> 6;
  const int wm = wid & 1, wn = wid >> 1;
  const int quad = lane >> 4, ln = lane & 15;

  floatx4 acc[4][4];
#pragma unroll
  for (int i = 0; i < 4; i++)
#pragma unroll
    for (int j = 0; j < 4; j++) acc[i][j] = (floatx4){0.f, 0.f, 0.f, 0.f};

  const int rr = tid >> 2;
  const int cc = (tid & 3) << 3;

  const ushort* a_src0 = a2 + ((size_t)(b * TT + t0 + rr)) * TT + cc;
  const ushort* a_src1 = a2 + ((size_t)(b * TT + t0 + rr + 64)) * TT + cc;
  const ushort* b_src0 = VvT + ((size_t)(b * VV + j0 + rr)) * TT + cc;
  const ushort* b_src1 = VvT + ((size_t)(b * VV + j0 + rr + 64)) * TT + cc;
  short* a_dst0 = &As[rr * LDT + cc];
  short* a_dst1 = &As[(rr + 64) * LDT + cc];
  short* b_dst0 = &Bs[rr * LDT + cc];
  short* b_dst1 = &Bs[(rr + 64) * LDT + cc];

#pragma unroll 1
  for (int kt = 0; kt < nk; ++kt) {
    const int soff = kt << 5;
    *(short8*)a_dst0 = *(const short8*)(a_src0 + soff);
    *(short8*)a_dst1 = *(const short8*)(a_src1 + soff);
    *(short8*)b_dst0 = *(const short8*)(b_src0 + soff);
    *(short8*)b_dst1 = *(const short8*)(b_src1 + soff);
    __syncthreads();
    short8 af[4], bf[4];
#pragma unroll
    for (int i = 0; i < 4; i++)
      af[i] = *(const short8*)&As[(wm * 64 + i * 16 + ln) * LDT + quad * 8];
#pragma unroll
    for (int j = 0; j < 4; j++)
      bf[j] = *(const short8*)&Bs[(wn * 64 + j * 16 + ln) * LDT + quad * 8];
#pragma unroll
    for (int i = 0; i < 4; i++)
#pragma unroll
      for (int j = 0; j < 4; j++)
        acc[i][j] = __builtin_amdgcn_mfma_f32_16x16x32_bf16(af[i], bf[j], acc[i][j], 0, 0, 0);
    __syncthreads();
  }

#pragma unroll
  for (int i = 0; i < 4; i++)
#pragma unroll
    for (int j = 0; j < 4; j++) {
      const int rowb = t0 + wm * 64 + i * 16 + quad * 4;
      const int col = j0 + wn * 64 + j * 16 + ln;
#pragma unroll
      for (int r = 0; r < 4; r++)
        out[((size_t)(b * TT + rowb + r)) * VV + col] = acc[i][j][r];
    }
}

extern "C" void kernel_launch(void* const* d_in, const int* in_sizes, int n_in,
                              void* d_out, int out_size, void* d_ws, size_t ws_size,
                              hipStream_t stream) {
  const int* idx = (const int*)d_in[0];
  const float* pos_table = (const float*)d_in[1];  // h[0..T-1]
  const float* Wq = (const float*)d_in[2];
  const float* Wv = (const float*)d_in[3];
  float* out = (float*)d_out;

  char* ws = (char*)d_ws;
  // ws layout (bytes):
  //   WqT  bf16 (V,V)      :        0 ..   524288
  //   l1   bf16 (B,T,V)    :   524288 .. 34078720
  //   VvT  bf16 (B,V,T)    : 34078720 .. 67633152
  //   a2   bf16 (B,T,T)    : 67633152 .. 201850880   (~193 MB total)
  //   PE   bf16 (T,T)      : aliases a2[0..8MB]     (dead before a2 written)
  //   ET   bf16 (B,V,T)    : aliases a2[8MB..40MB]  (dead before a2 written)
  ushort* WqT = (ushort*)(ws);
  ushort* l1 = (ushort*)(ws + 524288);
  ushort* VvT = (ushort*)(ws + 34078720UL);
  ushort* a2 = (ushort*)(ws + 67633152UL);
  ushort* PE = (ushort*)(ws + 67633152UL);
  ushort* ET = (ushort*)(ws + 67633152UL + 8388608UL);

  k_transpose_wq<<<dim3(VV), 256, 0, stream>>>(Wq, WqT);
  k_build_pe<<<dim3(TT), 256, 0, stream>>>(pos_table, PE);
  k_build_et<<<dim3(BB * VV), 256, 0, stream>>>(idx, ET);
  k_build_vvt<<<dim3(BB * VV), 256, 0, stream>>>(idx, Wv, VvT);
  k_gemm_l1<<<dim3(4, 16, BB), 256, 0, stream>>>(PE, ET, l1);
  k_gemm1<<<dim3(16, 16, BB), 256, 0, stream>>>(idx, WqT, l1, a2);
  k_gemm2<<<dim3(4, 16, BB), 256, 0, stream>>>(a2, VvT, out);
}

// Round 3
// 325.230 us; speedup vs baseline: 1.4088x; 1.1470x over previous
//
#include <hip/hip_runtime.h>
#include <hip/hip_bf16.h>

#define BB 16
#define TT 2048
#define VV 512

typedef __attribute__((ext_vector_type(8))) short short8;
typedef __attribute__((ext_vector_type(4))) float floatx4;

static __device__ inline ushort f2bf(float f) {
  __hip_bfloat16 h = __float2bfloat16(f);
  return *(ushort*)&h;
}

// async 16B global->LDS (direct DMA, no VGPR round-trip).
// HW semantics: dest = wave-uniform base + lane*16 — LDS layout must be
// contiguous in lane order (unpadded 64B-pitch rows, chunk n = tid).
static __device__ __forceinline__ void cp16(const void* g, void* l) {
  __builtin_amdgcn_global_load_lds((const __attribute__((address_space(1))) void*)g,
                                   (__attribute__((address_space(3))) void*)l, 16, 0, 0);
}

// ---------------- builders ----------------

// WqT[u][v] = Wq[v][u], bf16
__global__ __launch_bounds__(256) void k_transpose_wq(const float* __restrict__ Wq,
                                                      ushort* __restrict__ WqT) {
  int u = blockIdx.x;
  for (int v = threadIdx.x; v < VV; v += blockDim.x)
    WqT[u * VV + v] = f2bf(Wq[(size_t)v * VV + u]);
}

// PE[t][p] = (p <= t) ? bf16(h[t-p]) : 0   -- (T,T) bf16
__global__ __launch_bounds__(256) void k_build_pe(const float* __restrict__ h,
                                                  ushort* __restrict__ PE) {
  int t = blockIdx.x;
  ushort* out = PE + (size_t)t * TT;
  for (int p = threadIdx.x; p < TT; p += blockDim.x)
    out[p] = (p <= t) ? f2bf(h[t - p]) : (ushort)0;
}

// Fused: ET[b][v][p] = (idx[b,p]==v), VvT[b][v][s] = Wv[v][idx[b,s]]
__global__ __launch_bounds__(256) void k_build_etv(const int* __restrict__ idx,
                                                   const float* __restrict__ Wv,
                                                   ushort* __restrict__ ET,
                                                   ushort* __restrict__ VvT) {
  int bv = blockIdx.x;
  int b = bv >> 9, v = bv & (VV - 1);
  __shared__ float wrow[VV];
  for (int u = threadIdx.x; u < VV; u += blockDim.x) wrow[u] = Wv[(size_t)v * VV + u];
  __syncthreads();
  const int* row = idx + b * TT;
  ushort* oe = ET + (size_t)bv * TT;
  ushort* ov = VvT + (size_t)bv * TT;
  for (int s4 = threadIdx.x * 4; s4 < TT; s4 += blockDim.x * 4) {
    int4 iv = *(const int4*)(row + s4);
    ushort4 e, w;
    e.x = (iv.x == v) ? (ushort)0x3F80 : (ushort)0;  w.x = f2bf(wrow[iv.x]);
    e.y = (iv.y == v) ? (ushort)0x3F80 : (ushort)0;  w.y = f2bf(wrow[iv.y]);
    e.z = (iv.z == v) ? (ushort)0x3F80 : (ushort)0;  w.z = f2bf(wrow[iv.z]);
    e.w = (iv.w == v) ? (ushort)0x3F80 : (ushort)0;  w.w = f2bf(wrow[iv.w]);
    *(ushort4*)(oe + s4) = e;
    *(ushort4*)(ov + s4) = w;
  }
}

// ---------------- m97-style GEMM core (shared structure, copy per kernel) ----
// 128x128 C-tile, BK=32 bf16, unpadded LDS (pitch 32 shorts = 64B),
// global_load_lds 16B staging, XOR-swizzled k-chunks (4-way max conflicts).

#define GEMM_PRELUDE()                                                         \
  __shared__ __attribute__((aligned(16))) short As[128 * 32];                  \
  __shared__ __attribute__((aligned(16))) short Bs[128 * 32];                  \
  const int tid = threadIdx.x;                                                 \
  const int lane = tid & 63;                                                   \
  const int wm = (tid >> 6) & 1, wn = tid >> 7;                                \
  const int quad = lane >> 4, ln = lane & 15;                                  \
  const int rr = tid >> 2;                /* staging row 0..63 (and +64) */    \
  const int cg = (((tid & 3) ^ (rr & 3)) << 3); /* swizzled src chunk */       \
  short* a_dst = &As[tid * 8];                                                 \
  short* b_dst = &Bs[tid * 8];                                                 \
  const short* ap[4];                                                          \
  const short* bp[4];                                                          \
  _Pragma("unroll") for (int i = 0; i < 4; i++)                                \
      ap[i] = &As[(wm * 64 + i * 16 + ln) * 32 + ((quad ^ (ln & 3)) << 3)];    \
  _Pragma("unroll") for (int j = 0; j < 4; j++)                                \
      bp[j] = &Bs[(wn * 64 + j * 16 + ln) * 32 + ((quad ^ (ln & 3)) << 3)];

#define GEMM_KLOOP(NK)                                                         \
  _Pragma("unroll 1") for (int kt = 0; kt < (NK); ++kt) {                      \
    const int ko = kt << 5;                                                    \
    cp16(a_src0 + ko, a_dst);                                                  \
    cp16(a_src1 + ko, a_dst + 2048);                                           \
    cp16(b_src0 + ko, b_dst);                                                  \
    cp16(b_src1 + ko, b_dst + 2048);                                           \
    __syncthreads();                                                           \
    short8 af[4], bf[4];                                                       \
    _Pragma("unroll") for (int i = 0; i < 4; i++) af[i] = *(const short8*)ap[i]; \
    _Pragma("unroll") for (int j = 0; j < 4; j++) bf[j] = *(const short8*)bp[j]; \
    _Pragma("unroll") for (int i = 0; i < 4; i++)                              \
        _Pragma("unroll") for (int j = 0; j < 4; j++)                          \
            acc[i][j] =                                                        \
                __builtin_amdgcn_mfma_f32_16x16x32_bf16(af[i], bf[j], acc[i][j], 0, 0, 0); \
    __syncthreads();                                                           \
  }

#define ZERO_ACC()                                                             \
  _Pragma("unroll") for (int i = 0; i < 4; i++)                                \
      _Pragma("unroll") for (int j = 0; j < 4; j++)                            \
          acc[i][j] = (floatx4){0.f, 0.f, 0.f, 0.f};

// l1[b,t,v] = sum_p PE[t,p] * ET[b,v,p]  -- paired tiles (t_t=y and 15-y)
__global__ __launch_bounds__(256) void k_gemm_l1(const ushort* __restrict__ PE,
                                                 const ushort* __restrict__ ET,
                                                 ushort* __restrict__ l1) {
  const int v_t = blockIdx.x, pair = blockIdx.y, b = blockIdx.z;
  const int v0 = v_t << 7;
  GEMM_PRELUDE();
  const ushort* b_src0 = ET + ((size_t)((b << 9) + v0 + rr)) * TT + cg;
  const ushort* b_src1 = b_src0 + (size_t)64 * TT;
  floatx4 acc[4][4];
#pragma unroll 1
  for (int pass = 0; pass < 2; ++pass) {
    const int t_t = pass ? (15 - pair) : pair;
    const int t0 = t_t << 7;
    const int nk = (t_t << 2) + 4;
    const ushort* a_src0 = PE + (size_t)(t0 + rr) * TT + cg;
    const ushort* a_src1 = a_src0 + (size_t)64 * TT;
    ZERO_ACC();
    GEMM_KLOOP(nk);
#pragma unroll
    for (int i = 0; i < 4; i++)
#pragma unroll
      for (int j = 0; j < 4; j++) {
        const int rowb = t0 + wm * 64 + i * 16 + quad * 4;
        const int col = v0 + wn * 64 + j * 16 + ln;
#pragma unroll
        for (int r = 0; r < 4; r++)
          l1[((size_t)((b << 11) + rowb + r)) * VV + col] = f2bf(acc[i][j][r]);
      }
  }
}

// a2[b,t,s] = tril( WqT[idx[b,t]] . l1[b,s,:] )
__global__ __launch_bounds__(256) void k_gemm1(const int* __restrict__ idx,
                                               const ushort* __restrict__ WqT,
                                               const ushort* __restrict__ l1,
                                               ushort* __restrict__ a2) {
  const int s_t = blockIdx.x, t_t = blockIdx.y, b = blockIdx.z;
  if (s_t > t_t) return;
  const int t0 = t_t << 7, s0 = s_t << 7;
  GEMM_PRELUDE();
  const int u0 = idx[(b << 11) + t0 + rr];
  const int u1 = idx[(b << 11) + t0 + rr + 64];
  const ushort* a_src0 = WqT + (size_t)u0 * VV + cg;
  const ushort* a_src1 = WqT + (size_t)u1 * VV + cg;
  const ushort* b_src0 = l1 + ((size_t)((b << 11) + s0 + rr)) * VV + cg;
  const ushort* b_src1 = b_src0 + (size_t)64 * VV;
  floatx4 acc[4][4];
  ZERO_ACC();
  GEMM_KLOOP(16);
#pragma unroll
  for (int i = 0; i < 4; i++)
#pragma unroll
    for (int j = 0; j < 4; j++) {
      const int rowb = t0 + wm * 64 + i * 16 + quad * 4;
      const int col = s0 + wn * 64 + j * 16 + ln;
#pragma unroll
      for (int r = 0; r < 4; r++) {
        const int row = rowb + r;
        float v = acc[i][j][r];
        if (col > row) v = 0.f;
        a2[((size_t)((b << 11) + row)) * TT + col] = f2bf(v);
      }
    }
}

// logits[b,t,j] = sum_s a2[b,t,s] * VvT[b,j,s]  -- paired tiles, fp32 out
__global__ __launch_bounds__(256) void k_gemm2(const ushort* __restrict__ a2,
                                               const ushort* __restrict__ VvT,
                                               float* __restrict__ out) {
  const int j_t = blockIdx.x, pair = blockIdx.y, b = blockIdx.z;
  const int j0 = j_t << 7;
  GEMM_PRELUDE();
  const ushort* b_src0 = VvT + ((size_t)((b << 9) + j0 + rr)) * TT + cg;
  const ushort* b_src1 = b_src0 + (size_t)64 * TT;
  floatx4 acc[4][4];
#pragma unroll 1
  for (int pass = 0; pass < 2; ++pass) {
    const int t_t = pass ? (15 - pair) : pair;
    const int t0 = t_t << 7;
    const int nk = (t_t << 2) + 4;
    const ushort* a_src0 = a2 + ((size_t)((b << 11) + t0 + rr)) * TT + cg;
    const ushort* a_src1 = a_src0 + (size_t)64 * TT;
    ZERO_ACC();
    GEMM_KLOOP(nk);
#pragma unroll
    for (int i = 0; i < 4; i++)
#pragma unroll
      for (int j = 0; j < 4; j++) {
        const int rowb = t0 + wm * 64 + i * 16 + quad * 4;
        const int col = j0 + wn * 64 + j * 16 + ln;
#pragma unroll
        for (int r = 0; r < 4; r++)
          out[((size_t)((b << 11) + rowb + r)) * VV + col] = acc[i][j][r];
      }
  }
}

extern "C" void kernel_launch(void* const* d_in, const int* in_sizes, int n_in,
                              void* d_out, int out_size, void* d_ws, size_t ws_size,
                              hipStream_t stream) {
  const int* idx = (const int*)d_in[0];
  const float* pos_table = (const float*)d_in[1];
  const float* Wq = (const float*)d_in[2];
  const float* Wv = (const float*)d_in[3];
  float* out = (float*)d_out;

  char* ws = (char*)d_ws;
  // ws layout:
  //   WqT bf16 (V,V)   :        0 ..   524288
  //   l1  bf16 (B,T,V) :   524288 .. 34078720
  //   VvT bf16 (B,V,T) : 34078720 .. 67633152
  //   a2  bf16 (B,T,T) : 67633152 .. 201850880
  //   PE  bf16 (T,T)   : aliases a2[0..8MB]    (dead before a2 written)
  //   ET  bf16 (B,V,T) : aliases a2[8..40MB]   (dead before a2 written)
  ushort* WqT = (ushort*)(ws);
  ushort* l1 = (ushort*)(ws + 524288);
  ushort* VvT = (ushort*)(ws + 34078720UL);
  ushort* a2 = (ushort*)(ws + 67633152UL);
  ushort* PE = (ushort*)(ws + 67633152UL);
  ushort* ET = (ushort*)(ws + 67633152UL + 8388608UL);

  k_transpose_wq<<<dim3(VV), 256, 0, stream>>>(Wq, WqT);
  k_build_pe<<<dim3(TT), 256, 0, stream>>>(pos_table, PE);
  k_build_etv<<<dim3(BB * VV), 256, 0, stream>>>(idx, Wv, ET, VvT);
  k_gemm_l1<<<dim3(4, 8, BB), 256, 0, stream>>>(PE, ET, l1);
  k_gemm1<<<dim3(16, 16, BB), 256, 0, stream>>>(idx, WqT, l1, a2);
  k_gemm2<<<dim3(4, 8, BB), 256, 0, stream>>>(a2, VvT, out);
}